// Round 6
// baseline (292.911 us; speedup 1.0000x reference)
//
#include <hip/hip_runtime.h>

#define HDIM 256   // output hidden dim
#define KDIM 512   // 2*HDIM (concat)
#define ROWS 16    // batch rows per block
#define XPAD 4     // x row stride 516 floats (2064 B, 16B-aligned, 2-way banks)
#define HPAD 4     // hbuf row stride 260 floats
#define LN_EPS 1e-5f

// Kernel A: copy hidden2 -> out table region; init winner slots for touched nodes.
__global__ __launch_bounds__(256) void copy_init_kernel(
    const float4* __restrict__ src, float4* __restrict__ dst,
    int* __restrict__ winner, const int* __restrict__ node_batch,
    int n4, int B)
{
    int tid = blockIdx.x * blockDim.x + threadIdx.x;
    int stride = gridDim.x * blockDim.x;
    for (int i = tid; i < n4; i += stride) dst[i] = src[i];
    for (int i = tid; i < B; i += stride) winner[node_batch[i]] = -1;
}

// Kernel B: last-occurrence-wins via atomicMax over batch index.
__global__ __launch_bounds__(256) void winner_kernel(
    int* __restrict__ winner, const int* __restrict__ node_batch, int B)
{
    int i = blockIdx.x * blockDim.x + threadIdx.x;
    if (i < B) atomicMax(&winner[node_batch[i]], i);
}

// Kernel C: gather+mean -> f32 LDS -> col-split VALU GEMM -> hbuf -> LN -> stores.
// 512 threads = 8 waves, ROWS=16 rows/block.
// GEMM: wave w owns output cols [32w, 32w+32). Lane: row = lane&15,
//   cols c0 = 32w + (lane>>4)*8. Per k: 16 lanes broadcast-read one 32B W
//   segment (L1-hot). W2 is read ONCE per block -> 512 MB total L2 traffic
//   (vs round 3's 4 GB, which was the 116 us bottleneck).
// Epilogue: acc -> hbuf (f32 LDS), then the rounds-4/5 LN reader verbatim
//   (wave w reduces rows {w, w+8} with a 64-lane shuffle): clean bisect of
//   the hbuf-LN structure vs the MFMA path.
template <int SC>
__global__ __launch_bounds__(512, 4) void fused_kernel(
    const float* __restrict__ hidden1,
    const float* __restrict__ W2,      // [512][256] row-major f32
    const float* __restrict__ bias2,
    const float* __restrict__ gamma2,
    const float* __restrict__ beta2,
    const int* __restrict__ node_batch,
    const int* __restrict__ neigh2,
    const int* __restrict__ winner,
    float* __restrict__ out_h2,        // [B][256]
    float* __restrict__ out_tab,       // [N][256]
    int B, int S_rt)
{
    __shared__ float x[ROWS][KDIM + XPAD];     // 33 KB
    __shared__ float hbuf[ROWS][HDIM + HPAD];  // 16.6 KB
    const int t    = threadIdx.x;
    const int lane = t & 63;
    const int w    = t >> 6;           // wave id 0..7
    const int row0 = blockIdx.x * ROWS;

    // ---- stage 1: gather neighbors (mean) + self row -> f32 LDS (proven) ----
    #pragma unroll
    for (int rr = 0; rr < 2; ++rr) {
        const int r = w + rr * 8;
        int b = row0 + r;
        if (b >= B) b = B - 1;
        const int selfidx = node_batch[b];
        float4 a = make_float4(0.f, 0.f, 0.f, 0.f);
        if constexpr (SC > 0) {
            const int* nb = neigh2 + (size_t)b * SC;
            int idx[SC > 0 ? SC : 1];
            #pragma unroll
            for (int s = 0; s < SC; ++s) idx[s] = nb[s];
            #pragma unroll
            for (int s = 0; s < SC; ++s) {
                float4 v = *(const float4*)&hidden1[(size_t)idx[s] * HDIM + 4 * lane];
                a.x += v.x; a.y += v.y; a.z += v.z; a.w += v.w;
            }
            const float invS = 1.0f / (float)SC;
            a.x *= invS; a.y *= invS; a.z *= invS; a.w *= invS;
        } else {
            const int* nb = neigh2 + (size_t)b * S_rt;
            for (int s = 0; s < S_rt; ++s) {
                float4 v = *(const float4*)&hidden1[(size_t)nb[s] * HDIM + 4 * lane];
                a.x += v.x; a.y += v.y; a.z += v.z; a.w += v.w;
            }
            const float invS = 1.0f / (float)S_rt;
            a.x *= invS; a.y *= invS; a.z *= invS; a.w *= invS;
        }
        float4 sv = *(const float4*)&hidden1[(size_t)selfidx * HDIM + 4 * lane];
        *(float4*)&x[r][4 * lane]        = a;
        *(float4*)&x[r][HDIM + 4 * lane] = sv;
    }
    __syncthreads();

    // ---- stage 2: col-split VALU GEMM ----
    const int row = lane & 15;
    const int c0  = 32 * w + ((lane >> 4) << 3);
    float acc[8];
    #pragma unroll
    for (int j = 0; j < 8; ++j) acc[j] = 0.f;

    #pragma unroll 2
    for (int k = 0; k < KDIM; k += 4) {
        float4 xv = *(const float4*)&x[row][k];
        float xk[4] = {xv.x, xv.y, xv.z, xv.w};
        #pragma unroll
        for (int kk = 0; kk < 4; ++kk) {
            const float* wp = &W2[(size_t)(k + kk) * HDIM + c0];
            float4 w0 = *(const float4*)wp;
            float4 w1 = *(const float4*)(wp + 4);
            acc[0] = fmaf(xk[kk], w0.x, acc[0]);
            acc[1] = fmaf(xk[kk], w0.y, acc[1]);
            acc[2] = fmaf(xk[kk], w0.z, acc[2]);
            acc[3] = fmaf(xk[kk], w0.w, acc[3]);
            acc[4] = fmaf(xk[kk], w1.x, acc[4]);
            acc[5] = fmaf(xk[kk], w1.y, acc[5]);
            acc[6] = fmaf(xk[kk], w1.z, acc[6]);
            acc[7] = fmaf(xk[kk], w1.w, acc[7]);
        }
    }

    // (row, c0) is bijective over 512 threads: 16 rows x 32 col-groups.
    *(float4*)&hbuf[row][c0]     = make_float4(acc[0], acc[1], acc[2], acc[3]);
    *(float4*)&hbuf[row][c0 + 4] = make_float4(acc[4], acc[5], acc[6], acc[7]);
    __syncthreads();

    // ---- stage 3: bias + ReLU + LayerNorm + stores (rounds-4/5 reader) ----
    float4 bb = *(const float4*)&bias2[4 * lane];
    float4 gg = *(const float4*)&gamma2[4 * lane];
    float4 ee = *(const float4*)&beta2[4 * lane];
    float bbar[4] = {bb.x, bb.y, bb.z, bb.w};
    float gar[4]  = {gg.x, gg.y, gg.z, gg.w};
    float ear[4]  = {ee.x, ee.y, ee.z, ee.w};

    #pragma unroll
    for (int rr = 0; rr < 2; ++rr) {
        const int r = w + rr * 8;
        float4 hv = *(const float4*)&hbuf[r][4 * lane];
        float v[4];
        float s = 0.f, q = 0.f;
        {
            float hh[4] = {hv.x, hv.y, hv.z, hv.w};
            #pragma unroll
            for (int jj = 0; jj < 4; ++jj) {
                float h = fmaxf(hh[jj] + bbar[jj], 0.0f);
                v[jj] = h;
                s += h;
                q += h * h;
            }
        }
        #pragma unroll
        for (int off = 32; off > 0; off >>= 1) {
            s += __shfl_xor(s, off, 64);
            q += __shfl_xor(q, off, 64);
        }
        float mu   = s * (1.0f / (float)HDIM);
        float var  = q * (1.0f / (float)HDIM) - mu * mu;
        float rstd = rsqrtf(var + LN_EPS);

        int rowg = row0 + r;
        if (rowg < B) {
            float4 o;
            o.x = gar[0] * (v[0] - mu) * rstd + ear[0];
            o.y = gar[1] * (v[1] - mu) * rstd + ear[1];
            o.z = gar[2] * (v[2] - mu) * rstd + ear[2];
            o.w = gar[3] * (v[3] - mu) * rstd + ear[3];
            *(float4*)&out_h2[(size_t)rowg * HDIM + 4 * lane] = o;
            int node = node_batch[rowg];
            if (winner[node] == rowg)
                *(float4*)&out_tab[(size_t)node * HDIM + 4 * lane] = o;
        }
    }
}

extern "C" void kernel_launch(void* const* d_in, const int* in_sizes, int n_in,
                              void* d_out, int out_size, void* d_ws, size_t ws_size,
                              hipStream_t stream) {
    // Inputs (setup_inputs order):
    // 0 feats (UNUSED - layer1 dead code), 1 hidden1, 2 hidden2,
    // 3 W1, 4 b1, 5 g1, 6 be1 (unused), 7 W2, 8 b2, 9 g2, 10 be2,
    // 11 node_batch, 12 neigh1 (unused), 13 neigh2
    const float* hidden1 = (const float*)d_in[1];
    const float* hidden2 = (const float*)d_in[2];
    const float* W2      = (const float*)d_in[7];
    const float* b2      = (const float*)d_in[8];
    const float* g2      = (const float*)d_in[9];
    const float* be2     = (const float*)d_in[10];
    const int* node_batch = (const int*)d_in[11];
    const int* neigh2     = (const int*)d_in[13];

    const int B  = in_sizes[11];          // 16384
    const int S  = in_sizes[13] / B;      // 10
    const int NH = in_sizes[2];           // N*256 floats

    float* out_h2  = (float*)d_out;                       // [B,256]
    float* out_tab = out_h2 + (size_t)B * HDIM;           // [N,256]
    int*   winner  = (int*)d_ws;                          // N ints (proven layout)

    hipLaunchKernelGGL(copy_init_kernel, dim3(2048), dim3(256), 0, stream,
                       (const float4*)hidden2, (float4*)out_tab,
                       winner, node_batch, NH / 4, B);
    hipLaunchKernelGGL(winner_kernel, dim3((B + 255) / 256), dim3(256), 0, stream,
                       winner, node_batch, B);
    dim3 grid((B + ROWS - 1) / ROWS);
    if (S == 10) {
        hipLaunchKernelGGL((fused_kernel<10>), grid, dim3(512), 0, stream,
                           hidden1, W2, b2, g2, be2, node_batch, neigh2, winner,
                           out_h2, out_tab, B, S);
    } else {
        hipLaunchKernelGGL((fused_kernel<0>), grid, dim3(512), 0, stream,
                           hidden1, W2, b2, g2, be2, node_batch, neigh2, winner,
                           out_h2, out_tab, B, S);
    }
}